// Round 1
// baseline (1384.602 us; speedup 1.0000x reference)
//
#include <hip/hip_runtime.h>
#include <math.h>

#define Bb 2
#define Hh 8
#define Ss 512
#define Dd 64

typedef float floatx4 __attribute__((ext_vector_type(4)));

__global__ __launch_bounds__(256) void relattn_kernel(
    const float* __restrict__ Q, const float* __restrict__ Kmat,
    const float* __restrict__ V, const float* __restrict__ R,
    const int* __restrict__ mask, float* __restrict__ out,
    float* __restrict__ p_out)
{
    __shared__ float sq[Dd];
    __shared__ float ssc[Ss];
    __shared__ float sred[8];

    const int row = blockIdx.x;           // [0, B*H*S)
    const int q   = row & (Ss - 1);
    const int bh  = row >> 9;             // b*H + h
    const int b   = bh >> 3;              // H == 8
    const int tid = threadIdx.x;

    // stage q row in LDS
    if (tid < Dd) sq[tid] = Q[(size_t)row * Dd + tid];
    __syncthreads();

    // ---- Phase 1: scores[k] = (q . (K_k + R_qk)) / sqrt(D) ----
    const int j  = tid & 15;              // d-group: covers d = 4j..4j+3
    const int kg = tid >> 4;              // 16 k-groups per block
    const floatx4 qv = *(const floatx4*)&sq[j * 4];
    const float* Rrow = R    + (size_t)row * Ss * Dd;
    const float* Kbh  = Kmat + (size_t)bh  * Ss * Dd;

    for (int k = kg; k < Ss; k += 16) {
        floatx4 rv = __builtin_nontemporal_load(
            (const floatx4*)(Rrow + k * Dd + j * 4));
        floatx4 kv = *(const floatx4*)(Kbh + k * Dd + j * 4);
        float p = qv.x * (rv.x + kv.x) + qv.y * (rv.y + kv.y)
                + qv.z * (rv.z + kv.z) + qv.w * (rv.w + kv.w);
        // reduce across the 16-lane d-group (stays inside a wave)
        p += __shfl_xor(p, 1);
        p += __shfl_xor(p, 2);
        p += __shfl_xor(p, 4);
        p += __shfl_xor(p, 8);
        if (j == 0) ssc[k] = p * 0.125f;
    }
    __syncthreads();

    // ---- Phase 2: masked softmax over k (each thread owns k=tid, tid+256) ----
    const int* mrow = mask + (size_t)(b * Ss + q) * Ss;
    float s0 = ssc[tid], s1 = ssc[tid + 256];
    const int m0 = mrow[tid], m1 = mrow[tid + 256];
    if (m0 == 0) s0 = -1e9f;
    if (m1 == 0) s1 = -1e9f;

    float mx = fmaxf(s0, s1);
    #pragma unroll
    for (int o = 1; o < 64; o <<= 1) mx = fmaxf(mx, __shfl_xor(mx, o));
    if ((tid & 63) == 0) sred[tid >> 6] = mx;
    __syncthreads();
    mx = fmaxf(fmaxf(sred[0], sred[1]), fmaxf(sred[2], sred[3]));

    float e0 = __expf(s0 - mx);
    float e1 = __expf(s1 - mx);
    float sm = e0 + e1;
    #pragma unroll
    for (int o = 1; o < 64; o <<= 1) sm += __shfl_xor(sm, o);
    if ((tid & 63) == 0) sred[4 + (tid >> 6)] = sm;
    __syncthreads();
    sm = sred[4] + sred[5] + sred[6] + sred[7];

    const float inv = 1.0f / sm;
    const float p0 = (m0 == 0) ? 0.0f : e0 * inv;
    const float p1 = (m1 == 0) ? 0.0f : e1 * inv;

    float* prow = p_out + (size_t)row * Ss;
    prow[tid]       = p0;
    prow[tid + 256] = p1;

    // ---- Phase 3: out[q,:] = p . V ----
    ssc[tid]       = p0;       // each thread rewrites only its own entries
    ssc[tid + 256] = p1;
    __syncthreads();

    const int d = tid & 63;
    const int c = tid >> 6;               // 4 k-chunks of 128
    const float* Vbh = V + (size_t)bh * Ss * Dd;
    float acc = 0.0f;
    #pragma unroll 4
    for (int k = c * 128; k < c * 128 + 128; ++k)
        acc = fmaf(ssc[k], Vbh[k * Dd + d], acc);

    __syncthreads();
    ssc[tid] = acc;                       // reuse as chunk partials
    __syncthreads();
    if (tid < 64) {
        float r = ssc[tid] + ssc[64 + tid] + ssc[128 + tid] + ssc[192 + tid];
        out[(size_t)row * Dd + tid] = r;
    }
}

extern "C" void kernel_launch(void* const* d_in, const int* in_sizes, int n_in,
                              void* d_out, int out_size, void* d_ws, size_t ws_size,
                              hipStream_t stream) {
    const float* Q    = (const float*)d_in[0];
    const float* K    = (const float*)d_in[1];
    const float* V    = (const float*)d_in[2];
    const float* R    = (const float*)d_in[3];
    const int*   mask = (const int*)d_in[4];

    float* out   = (float*)d_out;
    float* p_out = out + (size_t)Bb * Hh * Ss * Dd;   // tuple order: out, p_attn

    relattn_kernel<<<Bb * Hh * Ss, 256, 0, stream>>>(Q, K, V, R, mask, out, p_out);
}

// Round 2
// 1290.613 us; speedup vs baseline: 1.0728x; 1.0728x over previous
//
#include <hip/hip_runtime.h>
#include <math.h>

#define Bb 2
#define Hh 8
#define Ss 512
#define Dd 64

typedef float floatx4 __attribute__((ext_vector_type(4)));

// One wave (64 lanes) owns one q-row end-to-end: scores -> softmax -> PV.
// No __syncthreads anywhere: all reductions are in-wave shuffles, the only
// LDS use is the per-wave score buffer (DS ops of a wave complete in order;
// wave_barrier() pins compiler ordering).
__global__ __launch_bounds__(256) void relattn_kernel(
    const float* __restrict__ Q, const float* __restrict__ Kmat,
    const float* __restrict__ V, const float* __restrict__ R,
    const int* __restrict__ mask, float* __restrict__ out,
    float* __restrict__ p_out)
{
    __shared__ float ssc_all[4][Ss];          // 8 KB: per-wave score buffer

    const int tid  = threadIdx.x;
    const int wave = tid >> 6;
    const int lane = tid & 63;
    float* ssc = ssc_all[wave];

    const int row = blockIdx.x * 4 + wave;    // [0, B*H*S)
    const int q   = row & (Ss - 1);
    const int bh  = row >> 9;                 // b*H + h
    const int b   = bh >> 3;                  // H == 8

    const int j  = lane & 15;                 // d4-group: d = 4j..4j+3
    const int kg = lane >> 4;                 // k-subgroup 0..3

    const floatx4 qv = *(const floatx4*)(Q + (size_t)row * Dd + j * 4);
    const float* Rrow = R    + (size_t)row * Ss * Dd;
    const float* Kbh  = Kmat + (size_t)bh  * Ss * Dd;
    const float* Vbh  = V    + (size_t)bh  * Ss * Dd;

    // ---- Phase 1: scores[k] = (q . (K_k + R_qk)) / 8 ----
    // Wave covers 4 consecutive k per iteration -> one contiguous 1 KiB R load.
    #pragma unroll 4
    for (int k = kg; k < Ss; k += 4) {
        floatx4 rv = __builtin_nontemporal_load(
            (const floatx4*)(Rrow + k * Dd + j * 4));
        floatx4 kv = *(const floatx4*)(Kbh + k * Dd + j * 4);
        float p = qv.x * (rv.x + kv.x) + qv.y * (rv.y + kv.y)
                + qv.z * (rv.z + kv.z) + qv.w * (rv.w + kv.w);
        p += __shfl_xor(p, 1);                // reduce across the 16-lane d-group
        p += __shfl_xor(p, 2);
        p += __shfl_xor(p, 4);
        p += __shfl_xor(p, 8);
        if (j == 0) ssc[k] = p * 0.125f;
    }
    __builtin_amdgcn_wave_barrier();

    // ---- Phase 2: wave-local masked softmax; lane owns k = lane + 64*i ----
    const int* mrow = mask + (size_t)(b * Ss + q) * Ss;
    float s[8]; int m[8];
    #pragma unroll
    for (int i = 0; i < 8; ++i) {
        m[i] = mrow[lane + 64 * i];
        s[i] = ssc[lane + 64 * i];            // bank = lane%32: conflict-free
        if (m[i] == 0) s[i] = -1e9f;
    }
    float mx = s[0];
    #pragma unroll
    for (int i = 1; i < 8; ++i) mx = fmaxf(mx, s[i]);
    #pragma unroll
    for (int o = 1; o < 64; o <<= 1) mx = fmaxf(mx, __shfl_xor(mx, o));

    float e[8], sm = 0.0f;
    #pragma unroll
    for (int i = 0; i < 8; ++i) { e[i] = __expf(s[i] - mx); sm += e[i]; }
    #pragma unroll
    for (int o = 1; o < 64; o <<= 1) sm += __shfl_xor(sm, o);
    const float inv = 1.0f / sm;

    float* prow = p_out + (size_t)row * Ss;
    #pragma unroll
    for (int i = 0; i < 8; ++i) {
        float p = (m[i] == 0) ? 0.0f : e[i] * inv;
        prow[lane + 64 * i] = p;              // coalesced 256 B stores
        ssc[lane + 64 * i]  = p;
    }
    __builtin_amdgcn_wave_barrier();

    // ---- Phase 3: out[row][:] = p . V, float4-vectorized (1 KiB/wave-instr) ----
    floatx4 acc = {0.f, 0.f, 0.f, 0.f};
    #pragma unroll 4
    for (int k = kg; k < Ss; k += 4) {
        float pk = ssc[k];                    // group-broadcast, conflict-free
        floatx4 vv = *(const floatx4*)(Vbh + k * Dd + j * 4);
        acc.x = fmaf(pk, vv.x, acc.x);
        acc.y = fmaf(pk, vv.y, acc.y);
        acc.z = fmaf(pk, vv.z, acc.z);
        acc.w = fmaf(pk, vv.w, acc.w);
    }
    // reduce across the 4 k-subgroups (lanes xor 16, 32)
    #pragma unroll
    for (int o = 16; o <= 32; o <<= 1) {
        acc.x += __shfl_xor(acc.x, o);
        acc.y += __shfl_xor(acc.y, o);
        acc.z += __shfl_xor(acc.z, o);
        acc.w += __shfl_xor(acc.w, o);
    }
    if (kg == 0)
        *(floatx4*)(out + (size_t)row * Dd + j * 4) = acc;
}

extern "C" void kernel_launch(void* const* d_in, const int* in_sizes, int n_in,
                              void* d_out, int out_size, void* d_ws, size_t ws_size,
                              hipStream_t stream) {
    const float* Q    = (const float*)d_in[0];
    const float* K    = (const float*)d_in[1];
    const float* V    = (const float*)d_in[2];
    const float* R    = (const float*)d_in[3];
    const int*   mask = (const int*)d_in[4];

    float* out   = (float*)d_out;
    float* p_out = out + (size_t)Bb * Hh * Ss * Dd;   // tuple order: out, p_attn

    relattn_kernel<<<(Bb * Hh * Ss) / 4, 256, 0, stream>>>(Q, K, V, R, mask, out, p_out);
}